// Round 13
// baseline (95.641 us; speedup 1.0000x reference)
//
#include <hip/hip_runtime.h>
#include <math.h>

// Problem constants (B=2, T=512, D=512)
#define NT   1024   // B*T tokens
#define TT   512    // T
#define DD   512    // D

// Extended Golay (24,12) generator, hardcoded (matches reference _golay()):
//   l <  12 : G[k][l] = (k==l)
//   l 12-22 : G[k][l] = (k+l)&1
//   l == 23 : G[k][l] = k&1
//
// PASSING STRATEGY (round 4, absmax 1.56e-2, stable r4-r12): faithful f32
// emulation of the f32 numpy reference — exact IEEE f32 ops (__f*_rn, no FMA
// contraction), correctly-rounded f32 sin/cos via f64 sincos, np.round =
// rintf, numpy's pairwise-summation order for norms, sequential-k fmaf GEMVs.
// DO NOT change any summation order that feeds round()/threshold decisions.
//
// FINAL CONFIG = ROUND 9 (best measured, 94.97 us), locked in after the
// experiment record showed a plateau:
//   r7 occupancy 2x: +0.6 | r8 wave-0 register Golay: +2.4 |
//   r9 4 tokens/block, grid=256=CUs, fully co-resident: +7.9 |
//   r10 in-kernel grid barrier: -7.3 (REGRESSION; dispatch beats spin) |
//   r11 W_dec LDS staging: -0.8 | r12 barrier shortening: -0.5
// Ceiling arithmetic: ~72us harness fixed cost (256MB ws poison fill runs
// at 84-85% HBM peak = at roofline; + restores/gaps), ~10us launch overhead
// (2 dispatches), ~13us kernel (f64-sincos VALU floor + cold first-touch
// weight loads + 7 data-dependency barriers). All remaining levers measured
// neutral-or-worse.

// numpy pairwise sum of 512 floats, exact numpy order (see r4). Runs on
// lanes 0..31 of the calling token's wave 0 (htid = thread-in-token).
// Result valid at htid == 0.
__device__ __forceinline__ float np_pairwise512(const float* x, int htid) {
    float r = 0.0f;
    if (htid < 32) {
        const int b = htid >> 3, j = htid & 7;
        const float* p = x + 128 * b + j;
        r = p[0];
        #pragma unroll
        for (int i = 1; i < 16; i++) r = __fadd_rn(r, p[8 * i]);
    }
    r = __fadd_rn(r, __shfl_down(r, 1, 64));
    r = __fadd_rn(r, __shfl_down(r, 2, 64));
    r = __fadd_rn(r, __shfl_down(r, 4, 64));
    r = __fadd_rn(r, __shfl_down(r, 8, 64));
    r = __fadd_rn(r, __shfl_down(r, 16, 64));
    return r;
}

// numpy pairwise sum, n=12 (8<=n<=128 path): combine first 8, then
// sequential remainder a[8..11].
__device__ __forceinline__ float np_pairwise12(const float* a) {
    float r = __fadd_rn(__fadd_rn(__fadd_rn(a[0], a[1]), __fadd_rn(a[2], a[3])),
                        __fadd_rn(__fadd_rn(a[4], a[5]), __fadd_rn(a[6], a[7])));
    r = __fadd_rn(r, a[8]);
    r = __fadd_rn(r, a[9]);
    r = __fadd_rn(r, a[10]);
    r = __fadd_rn(r, a[11]);
    return r;
}

__global__ __launch_bounds__(1024, 4) void token_kernel(
    const int*   __restrict__ token_ids,
    const float* __restrict__ resonances,
    const float* __restrict__ emb_scales,
    const float* __restrict__ emb_shifts,
    const float* __restrict__ emb_norm,
    const float* __restrict__ W_enc,   // [D,24] row-major
    const float* __restrict__ b_enc,   // [24]
    const float* __restrict__ W_dec,   // [24,D] row-major
    const float* __restrict__ b_dec,   // [D]
    const float* __restrict__ ecc_p,   // [1]
    const float* __restrict__ ep_p,    // [1]
    float*       __restrict__ out,     // [NT*D] f32 (scaled in place later)
    double*      __restrict__ partials)// [NT] per-token sum of squares
{
    const int tid  = threadIdx.x;
    const int q    = tid >> 8;        // token slot 0..3 (waves 4q..4q+3)
    const int htid = tid & 255;       // thread-in-token
    const int tok  = blockIdx.x * 4 + q;
    const int t    = tok % TT;
    const int w4   = htid >> 6;       // wave-in-token 0..3
    const int hlane = htid & 63;      // lane within wave (256-aligned split)

    __shared__ float  sh_w[DD * 24];   // staged W_enc (48 KB, shared by 4 tokens)
    __shared__ float  sh_e[4][DD];     // normalized emb
    __shared__ float  sh_x[4][DD];     // squares scratch
    __shared__ float  sh_c[4][24];     // corrected (decode output)
    __shared__ float  sh_sc[4][4];     // [q][0]: tok_norm, [2]: e_in2, [3]: e_out2
    __shared__ double sh_red[4][4];

    // ---- stage W_enc -> LDS (coalesced float4; hides under sincos; first
    //      consumer is after B3) ----
    {
        const float4* src = (const float4*)W_enc;
        float4*       dst = (float4*)sh_w;
        #pragma unroll
        for (int i = 0; i < 3; i++)           // 3 * 1024 = 3072 float4 = 48 KB
            dst[tid + 1024 * i] = src[tid + 1024 * i];
    }

    const float ecc   = ecc_p[0];
    const float ep    = ep_p[0];
    const float enorm = emb_norm[0];

    const int   idv  = token_ids[tok];                       // in [0,1e6): % identity
    const float tv   = __fdiv_rn((float)idv, 1000000.0f);    // exact np f32 div
    const float base = __fadd_rn(tv, (float)t);

    // ---- embedding (f32-exact): d0 = htid, d1 = htid+256 ----
    const int d0 = htid, d1 = htid + 256;
    float e0, e1;
    {
        const float a0 = __fmul_rn(resonances[d0], base);
        const float a1 = __fmul_rn(resonances[d1], base);
        // correctly-rounded f32 sin/cos via f64 sincos
        double s0d, c0d, s1d, c1d;
        sincos((double)a0, &s0d, &c0d);
        sincos((double)a1, &s1d, &c1d);
        const float s0 = (float)s0d, c0 = (float)c0d;
        const float s1 = (float)s1d, c1 = (float)c1d;
        const float comp0 = __fadd_rn(__fmul_rn(c0, __fadd_rn(1.0f, s0)), __fmul_rn(s0, s0));
        const float comp1 = __fadd_rn(__fmul_rn(c1, __fadd_rn(1.0f, s1)), __fmul_rn(s1, s1));
        e0 = __fadd_rn(__fmul_rn(comp0, emb_scales[d0]), emb_shifts[d0]);
        e1 = __fadd_rn(__fmul_rn(comp1, emb_scales[d1]), emb_shifts[d1]);
    }
    sh_x[q][d0] = __fmul_rn(e0, e0);
    sh_x[q][d1] = __fmul_rn(e1, e1);
    __syncthreads();                                         // B1

    // tok_norm (numpy pairwise + correctly-rounded sqrt)
    float ps = np_pairwise512(sh_x[q], htid);
    if (htid == 0) sh_sc[q][0] = __fsqrt_rn(ps);
    __syncthreads();                                         // B2
    const float tok_norm = sh_sc[q][0];
    if (tok_norm > 0.0f) {
        e0 = __fdiv_rn(__fmul_rn(e0, enorm), tok_norm);   // (emb*emb_norm)/tok_norm
        e1 = __fdiv_rn(__fmul_rn(e1, enorm), tok_norm);
    }
    sh_e[q][d0] = e0; sh_e[q][d1] = e1;
    sh_x[q][d0] = __fmul_rn(e0, e0);
    sh_x[q][d1] = __fmul_rn(e1, e1);
    __syncthreads();                                         // B3

    // e_in = ||normalized emb|| (reference recomputes it); valid at htid 0
    ps = np_pairwise512(sh_x[q], htid);
    const float e_in = __fsqrt_rn(ps);

    // ======== per-token wave-0 stretch: proj GEMV + Golay (registers) ======
    if (w4 == 0) {
        // proj = emb @ W_enc + b_enc (sequential-k FMA from LDS), lane l<24
        float p = 0.0f;
        if (hlane < 24) {
            float acc = 0.0f;
            #pragma unroll 8
            for (int d = 0; d < DD; d++)
                acc = fmaf(sh_e[q][d], sh_w[d * 24 + hlane], acc);
            p = __fadd_rn(acc, b_enc[hlane]);
        }

        // Golay encode + quantize (lanes 0..11), increasing-l order
        float latt = 0.0f;
        {
            const int k = hlane;
            float g = p;                         // l<12 terms: only l==k nonzero
            #pragma unroll
            for (int l = 12; l < 23; l++) {
                const float v = __shfl(p, l, 64);
                if ((k + l) & 1) g = __fadd_rn(g, v);
            }
            const float v23 = __shfl(p, 23, 64);
            if (k & 1) g = __fadd_rn(g, v23);
            latt = __fmul_rn(rintf(__fdiv_rn(g, ecc)), ecc);  // np.round = rint
        }

        // energy rescale (identical __f*_rn ops / order as r4-r12)
        float lt[12];
        #pragma unroll
        for (int k = 0; k < 12; k++) lt[k] = __shfl(latt, k, 64);
        float m1;
        {
            float sq[12];
            #pragma unroll
            for (int k = 0; k < 12; k++) sq[k] = __fmul_rn(lt[k], lt[k]);
            const float e_out = __fsqrt_rn(np_pairwise12(sq));
            m1 = __fdiv_rn(e_in, __fadd_rn(e_out, 1e-8f));    // e_in valid lane 0
        }
        m1 = __shfl(m1, 0, 64);                               // broadcast lane 0's m1
        float lv[12];
        #pragma unroll
        for (int k = 0; k < 12; k++) lv[k] = __fmul_rn(__fmul_rn(lt[k], m1), ep);
        if (hlane == 0) {
            float sq[12];
            #pragma unroll
            for (int k = 0; k < 12; k++) sq[k] = __fmul_rn(lv[k], lv[k]);
            sh_sc[q][2] = __fsqrt_rn(np_pairwise12(sq));   // e_in2 = ||scaled latt||
        }

        // Golay decode + ECC threshold (lanes 0..23), increasing-k order
        if (hlane < 24) {
            const int l = hlane;
            float g;
            if (l < 12) {
                g = lv[l];
            } else if (l < 23) {
                g = 0.0f;
                #pragma unroll
                for (int k = 0; k < 12; k++)
                    if ((k + l) & 1) g = __fadd_rn(g, lv[k]);
            } else {
                g = 0.0f;
                for (int k = 1; k < 12; k += 2) g = __fadd_rn(g, lv[k]);
            }
            sh_c[q][l] = (fabsf(g) > ecc) ? g : 0.0f;
        }
    }
    __syncthreads();                                         // B4

    // ---- res = corrected @ W_dec + b_dec (sequential-k FMA), then rescale ----
    float r0 = 0.0f, r1 = 0.0f;
    #pragma unroll
    for (int l = 0; l < 24; l++) {
        const float cl = sh_c[q][l];
        r0 = fmaf(cl, W_dec[l * DD + d0], r0);
        r1 = fmaf(cl, W_dec[l * DD + d1], r1);
    }
    r0 = __fadd_rn(r0, b_dec[d0]);
    r1 = __fadd_rn(r1, b_dec[d1]);
    sh_x[q][d0] = __fmul_rn(r0, r0);
    sh_x[q][d1] = __fmul_rn(r1, r1);
    __syncthreads();                                         // B5
    ps = np_pairwise512(sh_x[q], htid);
    if (htid == 0) sh_sc[q][3] = __fsqrt_rn(ps);    // e_out2
    __syncthreads();                                         // B6

    const float m2 = __fdiv_rn(sh_sc[q][2], __fadd_rn(sh_sc[q][3], 1e-8f));
    const float f0 = __fmul_rn(__fmul_rn(r0, m2), ep);
    const float f1 = __fmul_rn(__fmul_rn(r1, m2), ep);
    out[tok * DD + d0] = f0;
    out[tok * DD + d1] = f1;

    // ---- per-token sum of squares for ||res||_F (smooth: f64, no atomic) ----
    double v4 = (double)f0 * (double)f0 + (double)f1 * (double)f1;
    for (int off = 32; off > 0; off >>= 1) v4 += __shfl_down(v4, off, 64);
    if (hlane == 0) sh_red[q][w4] = v4;
    __syncthreads();                                         // B7
    if (htid == 0)
        partials[tok] = sh_red[q][0] + sh_red[q][1] + sh_red[q][2] + sh_red[q][3];
}

// In-place: out *= frac_norm * ||res||_F, factor redundantly reduced per
// block from the 1024 f64 partials (deterministic -> identical in every
// block; smooth scalar, order-insensitive).
// (fd cancels: _fractal_dimension returns fd*frac_norm*||res||/|fd| with
//  fd = clip(..,1,2.5) >= 1 > 0, so the factor is frac_norm*||res||_F up to
//  1 ulp; scale_weights / fractal_bias are provably dead inputs.)
__global__ __launch_bounds__(256) void scale_kernel(
    float*        __restrict__ out,
    const double* __restrict__ partials,
    const float*  __restrict__ frac_norm)
{
    const int tid = threadIdx.x;
    __shared__ double sh[4];
    __shared__ float sh_factor;
    double s = 0.0;
    #pragma unroll
    for (int i = 0; i < 4; i++) s += partials[tid + 256 * i];
    for (int off = 32; off > 0; off >>= 1) s += __shfl_down(s, off, 64);
    if ((tid & 63) == 0) sh[tid >> 6] = s;
    __syncthreads();
    if (tid == 0)
        sh_factor = (float)((double)frac_norm[0] * sqrt(sh[0] + sh[1] + sh[2] + sh[3]));
    __syncthreads();
    const float factor = sh_factor;

    const int i = blockIdx.x * blockDim.x + tid;   // one float4 per thread
    float4 r = ((const float4*)out)[i];
    r.x = __fmul_rn(r.x, factor);
    r.y = __fmul_rn(r.y, factor);
    r.z = __fmul_rn(r.z, factor);
    r.w = __fmul_rn(r.w, factor);
    ((float4*)out)[i] = r;
}

extern "C" void kernel_launch(void* const* d_in, const int* in_sizes, int n_in,
                              void* d_out, int out_size, void* d_ws, size_t ws_size,
                              hipStream_t stream)
{
    const int*   token_ids  = (const int*)  d_in[0];
    const float* resonances = (const float*)d_in[1];
    const float* emb_scales = (const float*)d_in[2];
    const float* emb_shifts = (const float*)d_in[3];
    const float* emb_norm   = (const float*)d_in[4];
    // d_in[5] scale_weights, d_in[6] fractal_bias: dead (fd cancellation)
    const float* frac_norm  = (const float*)d_in[7];
    const float* W_enc      = (const float*)d_in[8];
    const float* b_enc      = (const float*)d_in[9];
    const float* W_dec      = (const float*)d_in[10];
    const float* b_dec      = (const float*)d_in[11];
    const float* ecc        = (const float*)d_in[12];
    const float* ep         = (const float*)d_in[13];

    double* partials = (double*)d_ws;                       // 1024 doubles, all written

    token_kernel<<<NT / 4, 1024, 0, stream>>>(token_ids, resonances, emb_scales,
                                              emb_shifts, emb_norm, W_enc, b_enc,
                                              W_dec, b_dec, ecc, ep,
                                              (float*)d_out, partials);
    scale_kernel<<<(NT * DD) / 1024, 256, 0, stream>>>((float*)d_out, partials, frac_norm);
}